// Round 1
// baseline (229.388 us; speedup 1.0000x reference)
//
#include <hip/hip_runtime.h>
#include <cstdint>
#include <cstddef>

#define B_ 4
#define T_ 2048
#define C_ 1024
#define M_ (B_ * T_)   // 8192 rows
#define HALF_ 8
#define W_ 17
#define QKV_STRIDE 3072
#define NKS 64         // K / 16 (both GEMMs have K=1024)
#define NT 16          // K-tiles of BK=64

typedef unsigned short u16;
typedef _Float16 half8 __attribute__((ext_vector_type(8)));
typedef _Float16 half2_t __attribute__((ext_vector_type(2)));
typedef float f32x16 __attribute__((ext_vector_type(16)));

__device__ __forceinline__ float dot16(half8 a, half8 b, float acc) {
#if __has_builtin(__builtin_amdgcn_fdot2)
    const half2_t* pa = (const half2_t*)&a;
    const half2_t* pb = (const half2_t*)&b;
#pragma unroll
    for (int e = 0; e < 4; ++e) acc = __builtin_amdgcn_fdot2(pa[e], pb[e], acc, false);
#else
#pragma unroll
    for (int e = 0; e < 8; ++e) acc += (float)a[e] * (float)b[e];
#endif
    return acc;
}

__device__ __forceinline__ ushort4 cvt4(float4 v) {
    ushort4 o;
    _Float16 a = (_Float16)v.x; o.x = __builtin_bit_cast(unsigned short, a);
    _Float16 b = (_Float16)v.y; o.y = __builtin_bit_cast(unsigned short, b);
    _Float16 c = (_Float16)v.z; o.z = __builtin_bit_cast(unsigned short, c);
    _Float16 d = (_Float16)v.w; o.w = __builtin_bit_cast(unsigned short, d);
    return o;
}

// ================= fragment-major layout =================
// For mfma_f32_32x32x16_f16, operand chunk (tile mt, k-step ks) = 64 lanes
// x 8 halves contiguous at ((mt*64 + ks)*64 + lane)*8.
// Lane l holds Mat[row = mt*32 + (l&31)][k = ks*16 + (l>>5)*8 + e].
// One chunk = 1KB = exactly one global_load_lds_dwordx4 (wave-uniform LDS
// base + lane*16B) and one conflict-free ds_read_b128 per consumer wave.

// ---------------- fused prologue (unchanged) ----------------
__global__ void prologue(const float* __restrict__ x,
                         const float* __restrict__ Wq, const float* __restrict__ Wk,
                         const float* __restrict__ Wv, const float* __restrict__ Wo,
                         const float* __restrict__ bq, const float* __restrict__ bk,
                         const float* __restrict__ bv,
                         u16* __restrict__ xf, u16* __restrict__ wfq,
                         u16* __restrict__ wfo, float* __restrict__ bcat) {
    const int blk = blockIdx.x;
    const int tid = threadIdx.x;
    if (blk < 4096) {          // x -> frag-major: 16384 waves
        const int wid  = blk * 4 + (tid >> 6);
        const int lane = tid & 63;
        const int mt = wid >> 6;          // 0..255
        const int ks = wid & 63;
        const int row = mt * 32 + (lane & 31);
        const int col = ks * 16 + (lane >> 5) * 8;
        const float4* s = (const float4*)(x + (size_t)row * C_ + col);
        ushort4* d = (ushort4*)(xf + (((size_t)mt * 64 + ks) * 64 + lane) * 8);
        d[0] = cvt4(s[0]);
        d[1] = cvt4(s[1]);
        return;
    }
    if (blk >= 6144) {
        int i = (blk - 6144) * 256 + tid;
        const float* src = (i < 1024) ? bq : (i < 2048) ? bk : bv;
        bcat[i] = src[i & 1023];
        return;
    }
    // weights -> frag-major
    int c = (blk - 4096) * 256 + tid;   // 524288 chunks
    const float* src;
    u16* dst;
    int cc;
    if (c < 393216) {
        int mat = c / 131072;
        src = (mat == 0) ? Wq : (mat == 1) ? Wk : Wv;
        dst = wfq;  cc = c;  c = c % 131072;
    } else {
        src = Wo;  dst = wfo;  cc = c - 393216;  c = cc;
    }
    const int nt_local = c >> 12;
    const int ks   = (c >> 6) & 63;
    const int lane = c & 63;
    const int row = nt_local * 32 + (lane & 31);
    const int col = ks * 16 + (lane >> 5) * 8;
    const float4* s = (const float4*)(src + (size_t)row * C_ + col);
    ushort4* d = (ushort4*)(dst + (size_t)cc * 8);
    d[0] = cvt4(s[0]);
    d[1] = cvt4(s[1]);
}

// ---------------- LDS-staged pipelined GEMM ----------------
// BM=256 x BN=128 x BK=64 block tile, 8 waves (4M x 2N), wave = 64x64.
// Triple-buffered LDS (3 x 48KB = 144KB), stage tile kt+2 while computing
// tile kt -> counted s_waitcnt vmcnt(6) in the main loop (never drains),
// raw s_barrier (no implicit vmcnt(0) drain like __syncthreads).
// 2 phases per K-tile: {8 ds_read_b128 ; issue global_load_lds ; barrier ;
// setprio(1) ; 8 MFMA ; setprio(0) ; barrier}.

#define AS1_ __attribute__((address_space(1)))
#define AS3_ __attribute__((address_space(3)))

__device__ __forceinline__ void gload16(const u16* g, u16* l) {
    __builtin_amdgcn_global_load_lds((AS1_ void*)g, (AS3_ void*)l, 16, 0, 0);
}

#define MFMA_ __builtin_amdgcn_mfma_f32_32x32x16_f16

#define GEMM_ITER(CB, NB, KT)                                                  \
  {                                                                            \
    /* ---- phase 0: ks 0,1 of this K-tile ---- */                             \
    half8 a00 = *(const half8*)((CB) + offA0);                                 \
    half8 a01 = *(const half8*)((CB) + offA0 + 512);                           \
    half8 a10 = *(const half8*)((CB) + offA1);                                 \
    half8 a11 = *(const half8*)((CB) + offA1 + 512);                           \
    half8 p00 = *(const half8*)((CB) + offB0);                                 \
    half8 p01 = *(const half8*)((CB) + offB0 + 512);                           \
    half8 p10 = *(const half8*)((CB) + offB1);                                 \
    half8 p11 = *(const half8*)((CB) + offB1 + 512);                           \
    if ((KT) + 2 < NT) {                                                       \
      const size_t ko = (size_t)((KT) + 2) * 2048;                             \
      gload16(gs0 + ko, (NB) + lo0);                                           \
      gload16(gs1 + ko, (NB) + lo1);                                           \
      gload16(gs2 + ko, (NB) + lo2);                                           \
      gload16(gs3 + ko, (NB) + lo3);                                           \
    }                                                                          \
    asm volatile("s_barrier" ::: "memory");                                    \
    __builtin_amdgcn_s_setprio(1);                                             \
    acc00 = MFMA_(a00, p00, acc00, 0, 0, 0);                                   \
    acc01 = MFMA_(a00, p10, acc01, 0, 0, 0);                                   \
    acc10 = MFMA_(a10, p00, acc10, 0, 0, 0);                                   \
    acc11 = MFMA_(a10, p10, acc11, 0, 0, 0);                                   \
    acc00 = MFMA_(a01, p01, acc00, 0, 0, 0);                                   \
    acc01 = MFMA_(a01, p11, acc01, 0, 0, 0);                                   \
    acc10 = MFMA_(a11, p01, acc10, 0, 0, 0);                                   \
    acc11 = MFMA_(a11, p11, acc11, 0, 0, 0);                                   \
    __builtin_amdgcn_s_setprio(0);                                             \
    asm volatile("s_barrier" ::: "memory");                                    \
    /* ---- phase 1: ks 2,3 ---- */                                            \
    a00 = *(const half8*)((CB) + offA0 + 1024);                                \
    a01 = *(const half8*)((CB) + offA0 + 1536);                                \
    a10 = *(const half8*)((CB) + offA1 + 1024);                                \
    a11 = *(const half8*)((CB) + offA1 + 1536);                                \
    p00 = *(const half8*)((CB) + offB0 + 1024);                                \
    p01 = *(const half8*)((CB) + offB0 + 1536);                                \
    p10 = *(const half8*)((CB) + offB1 + 1024);                                \
    p11 = *(const half8*)((CB) + offB1 + 1536);                                \
    if ((KT) + 2 < NT) {                                                       \
      const size_t ko = (size_t)((KT) + 2) * 2048;                             \
      gload16(gs4 + ko, (NB) + lo4);                                           \
      gload16(gs5 + ko, (NB) + lo5);                                           \
    }                                                                          \
    asm volatile("s_barrier" ::: "memory");                                    \
    __builtin_amdgcn_s_setprio(1);                                             \
    acc00 = MFMA_(a00, p00, acc00, 0, 0, 0);                                   \
    acc01 = MFMA_(a00, p10, acc01, 0, 0, 0);                                   \
    acc10 = MFMA_(a10, p00, acc10, 0, 0, 0);                                   \
    acc11 = MFMA_(a10, p10, acc11, 0, 0, 0);                                   \
    acc00 = MFMA_(a01, p01, acc00, 0, 0, 0);                                   \
    acc01 = MFMA_(a01, p11, acc01, 0, 0, 0);                                   \
    acc10 = MFMA_(a11, p01, acc10, 0, 0, 0);                                   \
    acc11 = MFMA_(a11, p11, acc11, 0, 0, 0);                                   \
    __builtin_amdgcn_s_setprio(0);                                             \
    /* drain this tile's ds_reads BEFORE the barrier: next iter's staging */   \
    /* overwrites CB's buffer slot right after it. */                          \
    asm volatile("s_waitcnt lgkmcnt(0)" ::: "memory");                         \
    if ((KT) == NT - 2) asm volatile("s_waitcnt vmcnt(0)" ::: "memory");       \
    else                asm volatile("s_waitcnt vmcnt(6)" ::: "memory");       \
    asm volatile("s_barrier" ::: "memory");                                    \
  }

template <int OUT_F16>
__global__ __launch_bounds__(512, 2) void gemm_8ph(
    const u16* __restrict__ Afrag, const u16* __restrict__ Bfrag,
    const float* __restrict__ bias, void* __restrict__ Cout, int Ndim)
{
    __shared__ u16 lds[3][24576];   // 3 x 48KB: A 32KB (32 chunks) + B 16KB (16)
    const int tid  = threadIdx.x;
    const int lane = tid & 63;
    const int wave = tid >> 6;      // 0..7
    const int wm   = wave >> 1;     // 0..3  (M)
    const int wn   = wave & 1;      // 0..1  (N)
    const int bx = blockIdx.x, by = blockIdx.y;
    const int la8 = lane * 8;

    // consumer LDS offsets (u16 units): A chunk (mt_l,ks) at (mt_l*4+ks)*512,
    // B chunk (nt_l,ks) at 16384 + (nt_l*4+ks)*512
    const int offA0 = wm * 4096 + la8;           // mt_l = wm*2
    const int offA1 = offA0 + 2048;              // mt_l = wm*2+1
    const int offB0 = 16384 + wn * 4096 + la8;   // nt_l = wn*2
    const int offB1 = offB0 + 2048;              // nt_l = wn*2+1

    // staging: 48 chunks/K-tile, wave r-th chunk = wave + 8r
    const u16* gs0 = Afrag + ((size_t)(by*8 + ((wave+ 0)>>2))*64 + ((wave+ 0)&3))*512 + la8;
    const u16* gs1 = Afrag + ((size_t)(by*8 + ((wave+ 8)>>2))*64 + ((wave+ 8)&3))*512 + la8;
    const u16* gs2 = Afrag + ((size_t)(by*8 + ((wave+16)>>2))*64 + ((wave+16)&3))*512 + la8;
    const u16* gs3 = Afrag + ((size_t)(by*8 + ((wave+24)>>2))*64 + ((wave+24)&3))*512 + la8;
    const u16* gs4 = Bfrag + ((size_t)(bx*4 + ((wave+ 0)>>2))*64 + ((wave+ 0)&3))*512 + la8;
    const u16* gs5 = Bfrag + ((size_t)(bx*4 + ((wave+ 8)>>2))*64 + ((wave+ 8)&3))*512 + la8;
    const int lo0 = (wave +  0) * 512;
    const int lo1 = (wave +  8) * 512;
    const int lo2 = (wave + 16) * 512;
    const int lo3 = (wave + 24) * 512;
    const int lo4 = 16384 + (wave + 0) * 512;
    const int lo5 = 16384 + (wave + 8) * 512;

    u16* b0 = &lds[0][0];
    u16* b1 = &lds[1][0];
    u16* b2 = &lds[2][0];

    // pipeline prologue: stage tiles 0 and 1 (12 loads/thread); wait for
    // tile 0 only (vmcnt(6) leaves tile 1's 6 loads in flight)
    gload16(gs0, b0 + lo0); gload16(gs1, b0 + lo1); gload16(gs2, b0 + lo2);
    gload16(gs3, b0 + lo3); gload16(gs4, b0 + lo4); gload16(gs5, b0 + lo5);
    gload16(gs0 + 2048, b1 + lo0); gload16(gs1 + 2048, b1 + lo1);
    gload16(gs2 + 2048, b1 + lo2); gload16(gs3 + 2048, b1 + lo3);
    gload16(gs4 + 2048, b1 + lo4); gload16(gs5 + 2048, b1 + lo5);
    asm volatile("s_waitcnt vmcnt(6)" ::: "memory");
    asm volatile("s_barrier" ::: "memory");

    f32x16 acc00, acc01, acc10, acc11;
#pragma unroll
    for (int r = 0; r < 16; ++r) { acc00[r] = 0.f; acc01[r] = 0.f; acc10[r] = 0.f; acc11[r] = 0.f; }

    // tile kt lives in buf[kt%3]; iter kt stages tile kt+2 into buf[(kt+2)%3]
#pragma unroll 1
    for (int kt = 0; kt < NT - 1; kt += 3) {
        GEMM_ITER(b0, b2, kt);
        GEMM_ITER(b1, b0, kt + 1);
        GEMM_ITER(b2, b1, kt + 2);
    }
    GEMM_ITER(b0, b2, NT - 1);   // kt=15 (15%3==0), no staging left

    // C/D: col = lane&31, row = (reg&3) + 8*(reg>>2) + 4*(lane>>5)  [m74/m101]
    const int m0 = by * 256 + wm * 64;
    const int n0 = bx * 128 + wn * 64;
    f32x16 accs[2][2] = {{acc00, acc01}, {acc10, acc11}};
#pragma unroll
    for (int i = 0; i < 2; ++i) {
#pragma unroll
        for (int j = 0; j < 2; ++j) {
            const int col = n0 + j * 32 + (lane & 31);
            const float bv = bias[col];
#pragma unroll
            for (int reg = 0; reg < 16; ++reg) {
                const int row = m0 + i * 32 + (reg & 3) + 8 * (reg >> 2) + 4 * (lane >> 5);
                float val = accs[i][j][reg] + bv;
                if (OUT_F16) {
                    _Float16 h = (_Float16)val;
                    ((u16*)Cout)[(size_t)row * Ndim + col] = __builtin_bit_cast(unsigned short, h);
                } else {
                    ((float*)Cout)[(size_t)row * Ndim + col] = val;
                }
            }
        }
    }
}

// ---------------- windowed attention: one wave per token (unchanged) ----------------
__global__ __launch_bounds__(256) void attn_local(
    const u16* __restrict__ qkv, u16* __restrict__ ctxf)
{
    const int wid  = blockIdx.x * 4 + (threadIdx.x >> 6);
    const int lane = threadIdx.x & 63;
    const int b = wid >> 11;
    const int t = wid & (T_ - 1);
    const int base = b * T_;
    const size_t qrow = (size_t)(base + t) * QKV_STRIDE;
    const int c0 = lane * 8;

    half8 q0 = *(const half8*)(qkv + qrow + c0);
    half8 q1 = *(const half8*)(qkv + qrow + 512 + c0);

    float s[W_];
#pragma unroll
    for (int o = 0; o < W_; ++o) {
        int j = t - HALF_ + o;
        int jc = min(max(j, 0), T_ - 1);
        const size_t kb = (size_t)(base + jc) * QKV_STRIDE + 1024;
        half8 k0v = *(const half8*)(qkv + kb + c0);
        half8 k1v = *(const half8*)(qkv + kb + 512 + c0);
        float d = dot16(q1, k1v, dot16(q0, k0v, 0.f));
#pragma unroll
        for (int off = 32; off > 0; off >>= 1)
            d += __shfl_xor(d, off);
        s[o] = (j == jc) ? d * 0.03125f : -3.0e38f;
    }

    float mx = s[0];
#pragma unroll
    for (int o = 1; o < W_; ++o) mx = fmaxf(mx, s[o]);
    float den = 0.f;
#pragma unroll
    for (int o = 0; o < W_; ++o) den += __expf(s[o] - mx);
    const float inv = 1.f / den;

    float acc0[8], acc1[8];
#pragma unroll
    for (int e = 0; e < 8; ++e) { acc0[e] = 0.f; acc1[e] = 0.f; }
#pragma unroll
    for (int o = 0; o < W_; ++o) {
        int j = t - HALF_ + o;
        int jc = min(max(j, 0), T_ - 1);
        const float wt = __expf(s[o] - mx) * inv;
        const size_t vb_ = (size_t)(base + jc) * QKV_STRIDE + 2048;
        half8 v0 = *(const half8*)(qkv + vb_ + c0);
        half8 v1 = *(const half8*)(qkv + vb_ + 512 + c0);
#pragma unroll
        for (int e = 0; e < 8; ++e) {
            acc0[e] += wt * (float)v0[e];
            acc1[e] += wt * (float)v1[e];
        }
    }

    half8 o0, o1;
#pragma unroll
    for (int e = 0; e < 8; ++e) { o0[e] = (_Float16)acc0[e]; o1[e] = (_Float16)acc1[e]; }

    const int m = base + t;
    const int mt = m >> 5;
    const int rowin = (m & 31) + 32 * (lane & 1);
    const size_t ch0 = ((size_t)mt * 64 + (lane >> 1)) * 64 + rowin;       // ks = lane>>1
    const size_t ch1 = ((size_t)mt * 64 + 32 + (lane >> 1)) * 64 + rowin;  // ks = 32+lane>>1
    *(half8*)(ctxf + ch0 * 8) = o0;
    *(half8*)(ctxf + ch1 * 8) = o1;
}

// ---------------- host launch ----------------
extern "C" void kernel_launch(void* const* d_in, const int* in_sizes, int n_in,
                              void* d_out, int out_size, void* d_ws, size_t ws_size,
                              hipStream_t stream) {
    const float* x  = (const float*)d_in[0];
    const float* Wq = (const float*)d_in[1];
    const float* bq = (const float*)d_in[2];
    const float* Wk = (const float*)d_in[3];
    const float* bk = (const float*)d_in[4];
    const float* Wv = (const float*)d_in[5];
    const float* bv = (const float*)d_in[6];
    const float* Wo = (const float*)d_in[7];
    const float* bo = (const float*)d_in[8];
    float* out = (float*)d_out;

    u16* xf   = (u16*)d_ws;                         // 8M halves (frag-major)
    u16* wfq  = xf   + (size_t)M_ * C_;             // 3M  (Wq;Wk;Wv frag-major)
    u16* wfo  = wfq  + (size_t)3 * C_ * C_;         // 1M  (Wo frag-major)
    u16* qkvh = wfo  + (size_t)C_ * C_;             // 24M (M x 3072 row-major)
    u16* ctxf = qkvh + (size_t)M_ * QKV_STRIDE;     // 8M  (frag-major)
    float* bcat = (float*)(ctxf + (size_t)M_ * C_); // 3072 floats

    prologue<<<6156, 256, 0, stream>>>(x, Wq, Wk, Wv, Wo, bq, bk, bv,
                                       xf, wfq, wfo, bcat);

    dim3 gqkv(QKV_STRIDE / 128, M_ / 256);   // (24, 32) = 768 blocks, 3 CU rounds
    gemm_8ph<1><<<gqkv, 512, 0, stream>>>(xf, wfq, bcat, qkvh, QKV_STRIDE);

    attn_local<<<M_ / 4, 256, 0, stream>>>(qkvh, ctxf);   // 2048 blocks

    dim3 go(C_ / 128, M_ / 256);             // (8, 32) = 256 blocks, 1 CU round
    gemm_8ph<0><<<go, 512, 0, stream>>>(ctxf, wfo, bo, out, C_);
}

// Round 2
// 212.198 us; speedup vs baseline: 1.0810x; 1.0810x over previous
//
#include <hip/hip_runtime.h>
#include <cstdint>
#include <cstddef>

#define B_ 4
#define T_ 2048
#define C_ 1024
#define M_ (B_ * T_)   // 8192 rows
#define HALF_ 8
#define W_ 17
#define QKV_STRIDE 3072
#define NT 32          // K-tiles of BK=32 (K=1024 both GEMMs)

typedef unsigned short u16;
typedef _Float16 half8 __attribute__((ext_vector_type(8)));
typedef _Float16 half2_t __attribute__((ext_vector_type(2)));
typedef float f32x16 __attribute__((ext_vector_type(16)));
typedef unsigned short ushort8v __attribute__((ext_vector_type(8)));

__device__ __forceinline__ float dot16(half8 a, half8 b, float acc) {
#if __has_builtin(__builtin_amdgcn_fdot2)
    const half2_t* pa = (const half2_t*)&a;
    const half2_t* pb = (const half2_t*)&b;
#pragma unroll
    for (int e = 0; e < 4; ++e) acc = __builtin_amdgcn_fdot2(pa[e], pb[e], acc, false);
#else
#pragma unroll
    for (int e = 0; e < 8; ++e) acc += (float)a[e] * (float)b[e];
#endif
    return acc;
}

__device__ __forceinline__ ushort4 cvt4(float4 v) {
    ushort4 o;
    _Float16 a = (_Float16)v.x; o.x = __builtin_bit_cast(unsigned short, a);
    _Float16 b = (_Float16)v.y; o.y = __builtin_bit_cast(unsigned short, b);
    _Float16 c = (_Float16)v.z; o.z = __builtin_bit_cast(unsigned short, c);
    _Float16 d = (_Float16)v.w; o.w = __builtin_bit_cast(unsigned short, d);
    return o;
}

// ================= fragment-major layout =================
// For mfma_f32_32x32x16_f16, operand chunk (tile mt, k-step ks) = 64 lanes
// x 8 halves contiguous at ((mt*64 + ks)*64 + lane)*8.
// Lane l holds Mat[row = mt*32 + (l&31)][k = ks*16 + (l>>5)*8 + e].
// One chunk = 1KB = one global_load_lds_dwordx4 (wave-uniform LDS base +
// lane*16B) and one conflict-free ds_read_b128 per consumer wave.

// ---------------- prologue: coalesced LDS-transpose to frag-major --------
// Old version gathered 16B at 4KB row stride (32 cache lines/instr, ~4x
// over-fetch). New: coalesced float4 panel load -> fp16 -> XOR-swizzled LDS
// -> coalesced 16B frag-major stores.
// grid: [0,2048) x-panels (mt, kg); [2048,3072) weight panels; [3072,3084) bias.
__global__ void prologue2(const float* __restrict__ x,
                          const float* __restrict__ Wq, const float* __restrict__ Wk,
                          const float* __restrict__ Wv, const float* __restrict__ Wo,
                          const float* __restrict__ bq, const float* __restrict__ bk,
                          const float* __restrict__ bv,
                          u16* __restrict__ xf, u16* __restrict__ wfq,
                          u16* __restrict__ wfo, float* __restrict__ bcat) {
    const int blk = blockIdx.x;
    const int tid = threadIdx.x;
    if (blk >= 3072) {
        int i = (blk - 3072) * 256 + tid;
        const float* src = (i < 1024) ? bq : (i < 2048) ? bk : bv;
        bcat[i] = src[i & 1023];
        return;
    }
    __shared__ ushort8v g16[512];   // 32 rows x 16 granules(16B), XOR-swizzled: 8KB
    const float* src;
    u16* dst;
    size_t chunk_base;
    int kg;
    if (blk < 2048) {
        const int mt = blk >> 3; kg = blk & 7;
        src = x + (size_t)mt * 32 * C_;
        dst = xf; chunk_base = (size_t)mt * 64;
    } else {
        const int w = blk - 2048;
        const int mat = w >> 8, nt = (w >> 3) & 31; kg = w & 7;
        src = ((mat == 0) ? Wq : (mat == 1) ? Wk : (mat == 2) ? Wv : Wo)
              + (size_t)nt * 32 * C_;
        if (mat < 3) { dst = wfq; chunk_base = (size_t)(mat * 32 + nt) * 64; }
        else         { dst = wfo; chunk_base = (size_t)nt * 64; }
    }
    // load 32 rows x 128 cols fp32, coalesced: thread t -> row t>>3, 64B
    const int r = tid >> 3, gc = (tid & 7) * 2;
    const float4* s4 = (const float4*)(src + (size_t)r * C_ + kg * 128 + (tid & 7) * 16);
    float4 f0 = s4[0], f1 = s4[1], f2 = s4[2], f3 = s4[3];
    ushort4 h0 = cvt4(f0), h1 = cvt4(f1), h2 = cvt4(f2), h3 = cvt4(f3);
    ushort8v ga, gb;
    ga[0]=h0.x; ga[1]=h0.y; ga[2]=h0.z; ga[3]=h0.w;
    ga[4]=h1.x; ga[5]=h1.y; ga[6]=h1.z; ga[7]=h1.w;
    gb[0]=h2.x; gb[1]=h2.y; gb[2]=h2.z; gb[3]=h2.w;
    gb[4]=h3.x; gb[5]=h3.y; gb[6]=h3.z; gb[7]=h3.w;
    g16[r * 16 + ((gc    ) ^ (r & 15))] = ga;
    g16[r * 16 + ((gc + 1) ^ (r & 15))] = gb;
    __syncthreads();
    // emit 8 chunks (ks local 0..7), coalesced 1KB per wave
    const int lane = tid & 63, rr = lane & 31, hi = lane >> 5;
#pragma unroll
    for (int r2 = 0; r2 < 2; ++r2) {
        const int ksl = r2 * 4 + (tid >> 6);
        const int g = ksl * 2 + hi;
        ushort8v v = g16[rr * 16 + (g ^ (rr & 15))];
        *(ushort8v*)(dst + ((chunk_base + kg * 8 + ksl) * 64 + lane) * 8) = v;
    }
}

// ---------------- LDS-staged pipelined GEMM, v2 ----------------
// BM=256 x BN=128 x BK=32; 4 waves (2M x 2N), wave = 128x64 (intensity 43.7
// FLOP/LDS-byte vs 32 for 64x64). 3 LDS buffers x 24KB = 72KB -> 2 blocks/CU
// (cross-block TLP covers barrier bubbles; round-1's 1-block lockstep was the
// main MfmaUtil loss). Depth-2 prefetch, counted s_waitcnt vmcnt(6), raw
// s_barrier (1 per K-tile).

#define AS1_ __attribute__((address_space(1)))
#define AS3_ __attribute__((address_space(3)))

__device__ __forceinline__ void gload16(const u16* g, u16* l) {
    __builtin_amdgcn_global_load_lds((AS1_ void*)g, (AS3_ void*)l, 16, 0, 0);
}

#define MFMA_ __builtin_amdgcn_mfma_f32_32x32x16_f16

#define STAGE(NB, KT) { const size_t ko = (size_t)(KT) * 1024;            \
    gload16(gA0 + ko, (NB) + lA0); gload16(gA1 + ko, (NB) + lA1);         \
    gload16(gA2 + ko, (NB) + lA2); gload16(gA3 + ko, (NB) + lA3);         \
    gload16(gB0 + ko, (NB) + lB0); gload16(gB1 + ko, (NB) + lB1); }

#define TILE(CB, NB, KT, DOSTG, VW)                                        \
  {                                                                        \
    half8 a0 = *(const half8*)((CB) + oA);                                 \
    half8 a1 = *(const half8*)((CB) + oA + 1024);                          \
    half8 a2 = *(const half8*)((CB) + oA + 2048);                          \
    half8 a3 = *(const half8*)((CB) + oA + 3072);                          \
    half8 b0v = *(const half8*)((CB) + oB);                                \
    half8 b1v = *(const half8*)((CB) + oB + 1024);                         \
    if (DOSTG) STAGE(NB, (KT) + 2);                                        \
    __builtin_amdgcn_s_setprio(1);                                         \
    acc00 = MFMA_(a0, b0v, acc00, 0, 0, 0);                                \
    acc01 = MFMA_(a0, b1v, acc01, 0, 0, 0);                                \
    acc10 = MFMA_(a1, b0v, acc10, 0, 0, 0);                                \
    acc11 = MFMA_(a1, b1v, acc11, 0, 0, 0);                                \
    acc20 = MFMA_(a2, b0v, acc20, 0, 0, 0);                                \
    acc21 = MFMA_(a2, b1v, acc21, 0, 0, 0);                                \
    acc30 = MFMA_(a3, b0v, acc30, 0, 0, 0);                                \
    acc31 = MFMA_(a3, b1v, acc31, 0, 0, 0);                                \
    __builtin_amdgcn_s_setprio(0);                                         \
    a0 = *(const half8*)((CB) + oA + 512);                                 \
    a1 = *(const half8*)((CB) + oA + 1536);                                \
    a2 = *(const half8*)((CB) + oA + 2560);                                \
    a3 = *(const half8*)((CB) + oA + 3584);                                \
    b0v = *(const half8*)((CB) + oB + 512);                                \
    b1v = *(const half8*)((CB) + oB + 1536);                               \
    __builtin_amdgcn_s_setprio(1);                                         \
    acc00 = MFMA_(a0, b0v, acc00, 0, 0, 0);                                \
    acc01 = MFMA_(a0, b1v, acc01, 0, 0, 0);                                \
    acc10 = MFMA_(a1, b0v, acc10, 0, 0, 0);                                \
    acc11 = MFMA_(a1, b1v, acc11, 0, 0, 0);                                \
    acc20 = MFMA_(a2, b0v, acc20, 0, 0, 0);                                \
    acc21 = MFMA_(a2, b1v, acc21, 0, 0, 0);                                \
    acc30 = MFMA_(a3, b0v, acc30, 0, 0, 0);                                \
    acc31 = MFMA_(a3, b1v, acc31, 0, 0, 0);                                \
    __builtin_amdgcn_s_setprio(0);                                         \
    /* drain own ds_reads (WAR vs other block-waves' staging into CB's     \
       buffer next tile) + counted vmcnt: tile KT+1 staged, KT+2 in flight */ \
    if ((VW) == 6)      asm volatile("s_waitcnt vmcnt(6) lgkmcnt(0)" ::: "memory"); \
    else if ((VW) == 0) asm volatile("s_waitcnt vmcnt(0) lgkmcnt(0)" ::: "memory"); \
    else                asm volatile("s_waitcnt lgkmcnt(0)" ::: "memory"); \
    asm volatile("s_barrier" ::: "memory");                                \
  }

template <int OUT_F16>
__global__ __launch_bounds__(256, 2) void gemm_p2(
    const u16* __restrict__ Afrag, const u16* __restrict__ Bfrag,
    const float* __restrict__ bias, void* __restrict__ Cout, int Ndim)
{
    __shared__ u16 lds[3][12288];   // 3 x 24KB: A 16KB (16 chunks) + B 8KB (8)
    const int tid  = threadIdx.x;
    const int lane = tid & 63;
    const int wave = tid >> 6;      // 0..3
    const int wm   = wave >> 1;     // 0..1 (M half: 128 rows)
    const int wn   = wave & 1;      // 0..1 (N half: 64 cols)
    const int la8  = lane * 8;

    // bijective XCD swizzle (grid sizes are multiples of 8)
    const int nb  = gridDim.x * gridDim.y;
    int bid = blockIdx.y * gridDim.x + blockIdx.x;
    bid = (bid & 7) * (nb >> 3) + (bid >> 3);
    const int bx = bid % gridDim.x;
    const int by = bid / gridDim.x;

    // staging: 24 chunks/K-tile (A 16: id=mt_l*2+ks; B 8: id=nt_l*2+ks);
    // wave w stages A ids {w,w+4,w+8,w+12}, B ids {w,w+4}
    const u16* gA0 = Afrag + ((size_t)(by*8 + ((wave    )>>1))*64 + ((wave    )&1))*512 + la8;
    const u16* gA1 = Afrag + ((size_t)(by*8 + ((wave+ 4 )>>1))*64 + ((wave+ 4 )&1))*512 + la8;
    const u16* gA2 = Afrag + ((size_t)(by*8 + ((wave+ 8 )>>1))*64 + ((wave+ 8 )&1))*512 + la8;
    const u16* gA3 = Afrag + ((size_t)(by*8 + ((wave+12 )>>1))*64 + ((wave+12 )&1))*512 + la8;
    const u16* gB0 = Bfrag + ((size_t)(bx*4 + ((wave    )>>1))*64 + ((wave    )&1))*512 + la8;
    const u16* gB1 = Bfrag + ((size_t)(bx*4 + ((wave+ 4 )>>1))*64 + ((wave+ 4 )&1))*512 + la8;
    const int lA0 = (wave     ) * 512;
    const int lA1 = (wave +  4) * 512;
    const int lA2 = (wave +  8) * 512;
    const int lA3 = (wave + 12) * 512;
    const int lB0 = 8192 + (wave    ) * 512;
    const int lB1 = 8192 + (wave + 4) * 512;

    // consumer offsets (u16): A chunk (mt_l,ks) at (mt_l*2+ks)*512,
    // B chunk (nt_l,ks) at 8192 + (nt_l*2+ks)*512
    const int oA = wm * 4096 + la8;          // mt_l = wm*4 .. +3 (+1024 each), ks*512
    const int oB = 8192 + wn * 2048 + la8;   // nt_l = wn*2 .. +1 (+1024), ks*512

    u16* b0 = &lds[0][0];
    u16* b1 = &lds[1][0];
    u16* b2 = &lds[2][0];

    // pipeline prologue: stage tiles 0,1 (12 loads/thread); vmcnt(6) waits
    // tile 0 only
    STAGE(b0, 0);
    STAGE(b1, 1);
    asm volatile("s_waitcnt vmcnt(6)" ::: "memory");
    asm volatile("s_barrier" ::: "memory");

    f32x16 acc00, acc01, acc10, acc11, acc20, acc21, acc30, acc31;
#pragma unroll
    for (int r = 0; r < 16; ++r) {
        acc00[r] = 0.f; acc01[r] = 0.f; acc10[r] = 0.f; acc11[r] = 0.f;
        acc20[r] = 0.f; acc21[r] = 0.f; acc30[r] = 0.f; acc31[r] = 0.f;
    }

    // tile kt in buf[kt%3]; while computing kt, stage kt+2 into buf[(kt+2)%3]
#pragma unroll 1
    for (int kt = 0; kt < NT - 2; kt += 3) {
        TILE(b0, b2, kt,     1, 6);
        TILE(b1, b0, kt + 1, 1, 6);
        TILE(b2, b1, kt + 2, 1, 6);
    }
    TILE(b0, b2, NT - 2, 0, 0);    // kt=30: wait tile 31's staging fully
    TILE(b1, b2, NT - 1, 0, -1);   // kt=31: last

    // C/D: col = lane&31, row = (reg&3) + 8*(reg>>2) + 4*(lane>>5)  [m74/m101]
    const int m0 = by * 256 + wm * 128;
    const int n0 = bx * 128 + wn * 64;
    f32x16 accs[4][2] = {{acc00, acc01}, {acc10, acc11}, {acc20, acc21}, {acc30, acc31}};
#pragma unroll
    for (int i = 0; i < 4; ++i) {
#pragma unroll
        for (int j = 0; j < 2; ++j) {
            const int col = n0 + j * 32 + (lane & 31);
            const float bv = bias[col];
#pragma unroll
            for (int reg = 0; reg < 16; ++reg) {
                const int row = m0 + i * 32 + (reg & 3) + 8 * (reg >> 2) + 4 * (lane >> 5);
                float val = accs[i][j][reg] + bv;
                if (OUT_F16) {
                    _Float16 h = (_Float16)val;
                    ((u16*)Cout)[(size_t)row * Ndim + col] = __builtin_bit_cast(unsigned short, h);
                } else {
                    ((float*)Cout)[(size_t)row * Ndim + col] = val;
                }
            }
        }
    }
}

// ---------------- windowed attention: one wave per token (unchanged) ----------------
__global__ __launch_bounds__(256) void attn_local(
    const u16* __restrict__ qkv, u16* __restrict__ ctxf)
{
    const int wid  = blockIdx.x * 4 + (threadIdx.x >> 6);
    const int lane = threadIdx.x & 63;
    const int b = wid >> 11;
    const int t = wid & (T_ - 1);
    const int base = b * T_;
    const size_t qrow = (size_t)(base + t) * QKV_STRIDE;
    const int c0 = lane * 8;

    half8 q0 = *(const half8*)(qkv + qrow + c0);
    half8 q1 = *(const half8*)(qkv + qrow + 512 + c0);

    float s[W_];
#pragma unroll
    for (int o = 0; o < W_; ++o) {
        int j = t - HALF_ + o;
        int jc = min(max(j, 0), T_ - 1);
        const size_t kb = (size_t)(base + jc) * QKV_STRIDE + 1024;
        half8 k0v = *(const half8*)(qkv + kb + c0);
        half8 k1v = *(const half8*)(qkv + kb + 512 + c0);
        float d = dot16(q1, k1v, dot16(q0, k0v, 0.f));
#pragma unroll
        for (int off = 32; off > 0; off >>= 1)
            d += __shfl_xor(d, off);
        s[o] = (j == jc) ? d * 0.03125f : -3.0e38f;
    }

    float mx = s[0];
#pragma unroll
    for (int o = 1; o < W_; ++o) mx = fmaxf(mx, s[o]);
    float den = 0.f;
#pragma unroll
    for (int o = 0; o < W_; ++o) den += __expf(s[o] - mx);
    const float inv = 1.f / den;

    float acc0[8], acc1[8];
#pragma unroll
    for (int e = 0; e < 8; ++e) { acc0[e] = 0.f; acc1[e] = 0.f; }
#pragma unroll
    for (int o = 0; o < W_; ++o) {
        int j = t - HALF_ + o;
        int jc = min(max(j, 0), T_ - 1);
        const float wt = __expf(s[o] - mx) * inv;
        const size_t vb_ = (size_t)(base + jc) * QKV_STRIDE + 2048;
        half8 v0 = *(const half8*)(qkv + vb_ + c0);
        half8 v1 = *(const half8*)(qkv + vb_ + 512 + c0);
#pragma unroll
        for (int e = 0; e < 8; ++e) {
            acc0[e] += wt * (float)v0[e];
            acc1[e] += wt * (float)v1[e];
        }
    }

    half8 o0, o1;
#pragma unroll
    for (int e = 0; e < 8; ++e) { o0[e] = (_Float16)acc0[e]; o1[e] = (_Float16)acc1[e]; }

    const int m = base + t;
    const int mt = m >> 5;
    const int rowin = (m & 31) + 32 * (lane & 1);
    const size_t ch0 = ((size_t)mt * 64 + (lane >> 1)) * 64 + rowin;       // ks = lane>>1
    const size_t ch1 = ((size_t)mt * 64 + 32 + (lane >> 1)) * 64 + rowin;  // ks = 32+lane>>1
    *(half8*)(ctxf + ch0 * 8) = o0;
    *(half8*)(ctxf + ch1 * 8) = o1;
}

// ---------------- host launch ----------------
extern "C" void kernel_launch(void* const* d_in, const int* in_sizes, int n_in,
                              void* d_out, int out_size, void* d_ws, size_t ws_size,
                              hipStream_t stream) {
    const float* x  = (const float*)d_in[0];
    const float* Wq = (const float*)d_in[1];
    const float* bq = (const float*)d_in[2];
    const float* Wk = (const float*)d_in[3];
    const float* bk = (const float*)d_in[4];
    const float* Wv = (const float*)d_in[5];
    const float* bv = (const float*)d_in[6];
    const float* Wo = (const float*)d_in[7];
    const float* bo = (const float*)d_in[8];
    float* out = (float*)d_out;

    u16* xf   = (u16*)d_ws;                         // 8M halves (frag-major)
    u16* wfq  = xf   + (size_t)M_ * C_;             // 3M  (Wq;Wk;Wv frag-major)
    u16* wfo  = wfq  + (size_t)3 * C_ * C_;         // 1M  (Wo frag-major)
    u16* qkvh = wfo  + (size_t)C_ * C_;             // 24M (M x 3072 row-major)
    u16* ctxf = qkvh + (size_t)M_ * QKV_STRIDE;     // 8M  (frag-major)
    float* bcat = (float*)(ctxf + (size_t)M_ * C_); // 3072 floats

    prologue2<<<3084, 256, 0, stream>>>(x, Wq, Wk, Wv, Wo, bq, bk, bv,
                                        xf, wfq, wfo, bcat);

    dim3 gqkv(QKV_STRIDE / 128, M_ / 256);   // (24, 32) = 768 blocks, 3/CU
    gemm_p2<1><<<gqkv, 256, 0, stream>>>(xf, wfq, bcat, qkvh, QKV_STRIDE);

    attn_local<<<M_ / 4, 256, 0, stream>>>(qkvh, ctxf);   // 2048 blocks

    dim3 go(C_ / 128, M_ / 256);             // (8, 32) = 256 blocks
    gemm_p2<0><<<go, 256, 0, stream>>>(ctxf, wfo, bo, out, C_);
}